// Round 1
// baseline (139.008 us; speedup 1.0000x reference)
//
#include <hip/hip_runtime.h>

// Problem constants
#define DIM_W 160
#define DIM_H 192
#define DIM_D 160
#define DIM_B 2

constexpr int TW = 16;   // output tile width  (W)
constexpr int TH = 16;   // output tile height (H)
constexpr int CH = 40;   // depth chunk per block
constexpr int RW = TW + 8;  // 24: region width incl halo
constexpr int RH = TH + 8;  // 24: region height incl halo
constexpr float INV_K = 1.0f / 729.0f;
constexpr double NTOT = 9830400.0; // 2*160*192*160

__global__ void zero_out_kernel(float* out) { out[0] = 0.0f; }

__global__ __launch_bounds__(256)
void lncc3d_kernel(const float* __restrict__ I,
                   const float* __restrict__ T,
                   float* __restrict__ out) {
    __shared__ float sI[RH][RW + 1];   // +1 pad: avoid pow2 stride
    __shared__ float sT[RH][RW + 1];
    __shared__ float wsum[5][RH][TW];  // W-summed fields, field-major planes
    __shared__ float red[4];

    const int tid = threadIdx.x;
    const int bw = blockIdx.x;            // 0..9
    const int bh = blockIdx.y;            // 0..11
    const int bz = blockIdx.z;            // 0..7 : b*4 + chunk
    const int b  = bz >> 2;
    const int c  = bz & 3;
    const int w0 = bw * TW;
    const int h0 = bh * TH;
    const int d0 = c * CH;

    const size_t plane = (size_t)DIM_H * DIM_W;
    const float* Ib = I + (size_t)b * DIM_D * plane;
    const float* Tb = T + (size_t)b * DIM_D * plane;

    // 9-deep ring of per-slice 2D box sums (5 fields), plus running D-sums
    float rI[9], rT[9], rII[9], rTT[9], rIT[9];
#pragma unroll
    for (int j = 0; j < 9; ++j) { rI[j] = rT[j] = rII[j] = rTT[j] = rIT[j] = 0.0f; }
    float runI = 0.f, runT = 0.f, runII = 0.f, runTT = 0.f, runIT = 0.f;

    const int wo_t = tid & 15;   // this thread's output w within tile
    const int ho_t = tid >> 4;   // this thread's output h within tile
    float acc = 0.0f;

    for (int s = d0 - 4; s <= d0 + CH + 3; ++s) {
        const bool valid = (s >= 0) && (s < DIM_D);

        // ---- load slice halo region into LDS (zero-padded) ----
        if (valid) {
            const float* Is = Ib + (size_t)s * plane;
            const float* Ts = Tb + (size_t)s * plane;
            for (int i = tid; i < RH * RW; i += 256) {
                const int hh = i / RW;
                const int ww = i - hh * RW;
                const int gh = h0 - 4 + hh;
                const int gw = w0 - 4 + ww;
                float vi = 0.0f, vt = 0.0f;
                if (gh >= 0 && gh < DIM_H && gw >= 0 && gw < DIM_W) {
                    const size_t off = (size_t)gh * DIM_W + gw;
                    vi = Is[off];
                    vt = Ts[off];
                }
                sI[hh][ww] = vi;
                sT[hh][ww] = vt;
            }
        }
        __syncthreads();

        // ---- stage 1: 9-wide W sums of the 5 fields ----
        if (valid) {
            for (int p = tid; p < RH * TW; p += 256) {
                const int hh = p >> 4;       // 0..23
                const int wo = p & 15;       // 0..15
                float aI = 0.f, aT = 0.f, aII = 0.f, aTT = 0.f, aIT = 0.f;
#pragma unroll
                for (int k = 0; k < 9; ++k) {
                    const float iv = sI[hh][wo + k];
                    const float tv = sT[hh][wo + k];
                    aI += iv;
                    aT += tv;
                    aII = fmaf(iv, iv, aII);
                    aTT = fmaf(tv, tv, aTT);
                    aIT = fmaf(iv, tv, aIT);
                }
                wsum[0][hh][wo] = aI;
                wsum[1][hh][wo] = aT;
                wsum[2][hh][wo] = aII;
                wsum[3][hh][wo] = aTT;
                wsum[4][hh][wo] = aIT;
            }
        }
        __syncthreads();

        // ---- stage 2: 9-tall H sums at this thread's (ho_t, wo_t) ----
        float s2_0 = 0.f, s2_1 = 0.f, s2_2 = 0.f, s2_3 = 0.f, s2_4 = 0.f;
        if (valid) {
#pragma unroll
            for (int k = 0; k < 9; ++k) {
                s2_0 += wsum[0][ho_t + k][wo_t];
                s2_1 += wsum[1][ho_t + k][wo_t];
                s2_2 += wsum[2][ho_t + k][wo_t];
                s2_3 += wsum[3][ho_t + k][wo_t];
                s2_4 += wsum[4][ho_t + k][wo_t];
            }
        }

        // ---- D-direction: running sums + 9-deep register ring ----
        runI  += s2_0 - rI[0];
        runT  += s2_1 - rT[0];
        runII += s2_2 - rII[0];
        runTT += s2_3 - rTT[0];
        runIT += s2_4 - rIT[0];
#pragma unroll
        for (int j = 0; j < 8; ++j) {
            rI[j] = rI[j + 1]; rT[j] = rT[j + 1]; rII[j] = rII[j + 1];
            rTT[j] = rTT[j + 1]; rIT[j] = rIT[j + 1];
        }
        rI[8] = s2_0; rT[8] = s2_1; rII[8] = s2_2; rTT[8] = s2_3; rIT[8] = s2_4;

        // ---- emit output for depth s-4 once window complete ----
        if (s >= d0 + 4) {
            const float x     = runI * runT * INV_K;
            const float cross = runIT - x;
            const float i_var = runII - runI * runI * INV_K;
            const float t_var = runTT - runT * runT * INV_K;
            const float cc = cross * cross / (t_var * i_var + 1e-5f);
            acc += cc;
        }
    }

    // ---- block reduction ----
#pragma unroll
    for (int off = 32; off > 0; off >>= 1) acc += __shfl_down(acc, off, 64);
    if ((tid & 63) == 0) red[tid >> 6] = acc;
    __syncthreads();
    if (tid == 0) {
        const float bs = red[0] + red[1] + red[2] + red[3];
        atomicAdd(out, bs * (float)(-1.0 / NTOT));
    }
}

extern "C" void kernel_launch(void* const* d_in, const int* in_sizes, int n_in,
                              void* d_out, int out_size, void* d_ws, size_t ws_size,
                              hipStream_t stream) {
    const float* I = (const float*)d_in[0];
    const float* T = (const float*)d_in[1];
    float* out = (float*)d_out;

    zero_out_kernel<<<dim3(1), dim3(1), 0, stream>>>(out);

    dim3 grid(DIM_W / TW, DIM_H / TH, DIM_B * (DIM_D / CH)); // 10 x 12 x 8
    dim3 block(256);
    lncc3d_kernel<<<grid, block, 0, stream>>>(I, T, out);
}

// Round 2
// 101.534 us; speedup vs baseline: 1.3691x; 1.3691x over previous
//
#include <hip/hip_runtime.h>

// Problem constants
#define DIM_W 160
#define DIM_H 192
#define DIM_D 160
#define DIM_B 2

constexpr int TW = 16;   // output tile width  (W)
constexpr int TH = 32;   // output tile height (H) -- 2 pixels per thread
constexpr int CH = 40;   // depth chunk per block
constexpr int RW = 32;   // region width incl halo, padded to float4-aligned (covers w0-8 .. w0+23)
constexpr int RH = TH + 8;  // 40: region height incl halo
constexpr float INV_K = 1.0f / 729.0f;
constexpr double NTOT = 9830400.0; // 2*160*192*160

__global__ void zero_out_kernel(float* out) { out[0] = 0.0f; }

__global__ __launch_bounds__(256)
void lncc3d_kernel(const float* __restrict__ I,
                   const float* __restrict__ T,
                   float* __restrict__ out) {
    // raw slice region, row stride 36 words (144B = 16B-aligned, banks rotate by 4/row)
    __shared__ __align__(16) float sI[RH][36];
    __shared__ __align__(16) float sT[RH][36];
    // W-summed fields: (I,T,II,TT) packed float4, stride 17 float4s (even bank spread)
    __shared__ float4 wA[RH][17];
    // IT W-sums, stride 21 words (<=2-way aliasing)
    __shared__ float  wB[RH][21];
    __shared__ float red[4];

    const int tid = threadIdx.x;
    const int bw = blockIdx.x;            // 0..9
    const int bh = blockIdx.y;            // 0..5
    const int bz = blockIdx.z;            // 0..7 : b*4 + chunk
    const int b  = bz >> 2;
    const int c  = bz & 3;
    const int w0 = bw * TW;
    const int h0 = bh * TH;
    const int d0 = c * CH;

    const size_t plane = (size_t)DIM_H * DIM_W;
    const float* Ib = I + (size_t)b * DIM_D * plane;
    const float* Tb = T + (size_t)b * DIM_D * plane;

    // per-thread: 2 output pixels (local h = 2*st, 2*st+1), column (h,w) fixed, slide over d
    const int wo = tid & 15;        // output w within tile
    const int st = tid >> 4;        // strip index 0..15 -> local h base 2*st
    const int hb = st << 1;

    // 9-deep D-rings + running sums for 5 fields x 2 pixels
    float rgI[2][9], rgT[2][9], rgII[2][9], rgTT[2][9], rgIT[2][9];
    float rnI[2], rnT[2], rnII[2], rnTT[2], rnIT[2];
#pragma unroll
    for (int p = 0; p < 2; ++p) {
        rnI[p] = rnT[p] = rnII[p] = rnTT[p] = rnIT[p] = 0.0f;
#pragma unroll
        for (int j = 0; j < 9; ++j) {
            rgI[p][j] = rgT[p][j] = rgII[p][j] = rgTT[p][j] = rgIT[p][j] = 0.0f;
        }
    }
    float acc = 0.0f;

    for (int s = d0 - 4; s <= d0 + CH + 3; ++s) {
        const bool valid = (s >= 0) && (s < DIM_D);

        // ---- load slice region (40 rows x 32 floats x 2 fields) as float4 ----
        if (valid) {
            const float* Is = Ib + (size_t)s * plane;
            const float* Ts = Tb + (size_t)s * plane;
            for (int i = tid; i < 320; i += 256) {
                const int r  = i >> 3;
                const int c4 = i & 7;
                const int gh = h0 - 4 + r;
                const int gw = w0 - 8 + (c4 << 2);
                float4 vi = make_float4(0.f, 0.f, 0.f, 0.f);
                float4 vt = make_float4(0.f, 0.f, 0.f, 0.f);
                if (gh >= 0 && gh < DIM_H && gw >= 0 && gw <= DIM_W - 4) {
                    const size_t off = (size_t)gh * DIM_W + gw;
                    vi = *reinterpret_cast<const float4*>(Is + off);
                    vt = *reinterpret_cast<const float4*>(Ts + off);
                }
                *reinterpret_cast<float4*>(&sI[r][c4 << 2]) = vi;
                *reinterpret_cast<float4*>(&sT[r][c4 << 2]) = vt;
            }
        }
        __syncthreads();

        // ---- stage 1: 9-wide W sums, 4-output groups, sliding window ----
        if (valid && tid < 160) {
            const int r = tid >> 2;   // region row 0..39
            const int g = tid & 3;    // w-group 0..3 (outputs 4g..4g+3)
            const float4 ia = *reinterpret_cast<const float4*>(&sI[r][(g + 1) << 2]);
            const float4 ib = *reinterpret_cast<const float4*>(&sI[r][(g + 2) << 2]);
            const float4 ic = *reinterpret_cast<const float4*>(&sI[r][(g + 3) << 2]);
            const float4 ta = *reinterpret_cast<const float4*>(&sT[r][(g + 1) << 2]);
            const float4 tb = *reinterpret_cast<const float4*>(&sT[r][(g + 2) << 2]);
            const float4 tc = *reinterpret_cast<const float4*>(&sT[r][(g + 3) << 2]);
            float iv[12] = {ia.x, ia.y, ia.z, ia.w, ib.x, ib.y, ib.z, ib.w, ic.x, ic.y, ic.z, ic.w};
            float tv[12] = {ta.x, ta.y, ta.z, ta.w, tb.x, tb.y, tb.z, tb.w, tc.x, tc.y, tc.z, tc.w};

            float aI = 0.f, aT = 0.f, aII = 0.f, aTT = 0.f, aIT = 0.f;
#pragma unroll
            for (int k = 0; k < 9; ++k) {
                aI += iv[k];
                aT += tv[k];
                aII = fmaf(iv[k], iv[k], aII);
                aTT = fmaf(tv[k], tv[k], aTT);
                aIT = fmaf(iv[k], tv[k], aIT);
            }
            wA[r][(g << 2)] = make_float4(aI, aT, aII, aTT);
            wB[r][(g << 2)] = aIT;
#pragma unroll
            for (int j = 1; j < 4; ++j) {
                const float ni = iv[8 + j], oi = iv[j - 1];
                const float nt = tv[8 + j], ot = tv[j - 1];
                aI += ni - oi;
                aT += nt - ot;
                aII = fmaf(ni, ni, fmaf(oi, -oi, aII));
                aTT = fmaf(nt, nt, fmaf(ot, -ot, aTT));
                aIT = fmaf(ni, nt, fmaf(oi, -ot, aIT));
                wA[r][(g << 2) + j] = make_float4(aI, aT, aII, aTT);
                wB[r][(g << 2) + j] = aIT;
            }
        }
        __syncthreads();

        // ---- stage 2: 9-tall H sums for 2 stacked pixels (10 rows, window overlap) ----
        float s2I[2], s2T[2], s2II[2], s2TT[2], s2IT[2];
        s2I[0] = s2T[0] = s2II[0] = s2TT[0] = s2IT[0] = 0.f;
        s2I[1] = s2T[1] = s2II[1] = s2TT[1] = s2IT[1] = 0.f;
        if (valid) {
            const float4 A0 = wA[hb][wo];
            const float  b0 = wB[hb][wo];
            float4 S = A0;
            float  sb = b0;
#pragma unroll
            for (int k = 1; k < 9; ++k) {
                const float4 A = wA[hb + k][wo];
                S.x += A.x; S.y += A.y; S.z += A.z; S.w += A.w;
                sb += wB[hb + k][wo];
            }
            const float4 A9 = wA[hb + 9][wo];
            const float  b9 = wB[hb + 9][wo];
            s2I[0] = S.x; s2T[0] = S.y; s2II[0] = S.z; s2TT[0] = S.w; s2IT[0] = sb;
            s2I[1]  = S.x - A0.x + A9.x;
            s2T[1]  = S.y - A0.y + A9.y;
            s2II[1] = S.z - A0.z + A9.z;
            s2TT[1] = S.w - A0.w + A9.w;
            s2IT[1] = sb  - b0   + b9;
        }

        // ---- D-direction: running sums + 9-deep register rings ----
#pragma unroll
        for (int p = 0; p < 2; ++p) {
            rnI[p]  += s2I[p]  - rgI[p][0];
            rnT[p]  += s2T[p]  - rgT[p][0];
            rnII[p] += s2II[p] - rgII[p][0];
            rnTT[p] += s2TT[p] - rgTT[p][0];
            rnIT[p] += s2IT[p] - rgIT[p][0];
#pragma unroll
            for (int j = 0; j < 8; ++j) {
                rgI[p][j] = rgI[p][j + 1]; rgT[p][j] = rgT[p][j + 1];
                rgII[p][j] = rgII[p][j + 1]; rgTT[p][j] = rgTT[p][j + 1];
                rgIT[p][j] = rgIT[p][j + 1];
            }
            rgI[p][8] = s2I[p]; rgT[p][8] = s2T[p]; rgII[p][8] = s2II[p];
            rgTT[p][8] = s2TT[p]; rgIT[p][8] = s2IT[p];
        }

        // ---- emit once D-window complete ----
        if (s >= d0 + 4) {
#pragma unroll
            for (int p = 0; p < 2; ++p) {
                const float cross = rnIT[p] - rnI[p] * rnT[p] * INV_K;
                const float i_var = rnII[p] - rnI[p] * rnI[p] * INV_K;
                const float t_var = rnTT[p] - rnT[p] * rnT[p] * INV_K;
                acc += cross * cross / (t_var * i_var + 1e-5f);
            }
        }
    }

    // ---- block reduction ----
#pragma unroll
    for (int off = 32; off > 0; off >>= 1) acc += __shfl_down(acc, off, 64);
    if ((tid & 63) == 0) red[tid >> 6] = acc;
    __syncthreads();
    if (tid == 0) {
        const float bs = red[0] + red[1] + red[2] + red[3];
        atomicAdd(out, bs * (float)(-1.0 / NTOT));
    }
}

extern "C" void kernel_launch(void* const* d_in, const int* in_sizes, int n_in,
                              void* d_out, int out_size, void* d_ws, size_t ws_size,
                              hipStream_t stream) {
    const float* I = (const float*)d_in[0];
    const float* T = (const float*)d_in[1];
    float* out = (float*)d_out;

    zero_out_kernel<<<dim3(1), dim3(1), 0, stream>>>(out);

    dim3 grid(DIM_W / TW, DIM_H / TH, DIM_B * (DIM_D / CH)); // 10 x 6 x 8 = 480
    dim3 block(256);
    lncc3d_kernel<<<grid, block, 0, stream>>>(I, T, out);
}

// Round 3
// 91.383 us; speedup vs baseline: 1.5212x; 1.1111x over previous
//
#include <hip/hip_runtime.h>

// Problem constants
#define DIM_W 160
#define DIM_H 192
#define DIM_D 160
#define DIM_B 2

constexpr int TW = 16;      // output tile width  (W)
constexpr int TH = 32;      // output tile height (H) -- 2 pixels per thread
constexpr int CH = 19;      // depth outputs per chunk (27 slices = 3 x unroll-9)
constexpr int NCH = 9;      // ceil(160/19)
constexpr int RH = TH + 8;  // 40 region rows incl halo
constexpr int RS = 36;      // region row stride in floats (144B, 16B-aligned)
constexpr float INV_K = 1.0f / 729.0f;
constexpr double NTOT = 9830400.0; // 2*160*192*160

__global__ void zero_out_kernel(float* out) { out[0] = 0.0f; }

__global__ __launch_bounds__(256)
void lncc3d_kernel(const float* __restrict__ I,
                   const float* __restrict__ T,
                   float* __restrict__ out) {
    // double-buffered raw slice region: [buf][field][row][col]
    __shared__ __align__(16) float sR[2][2][RH][RS];
    // W-summed (I,T,II,TT) packed float4, stride 17 f4
    __shared__ float4 wA[RH][17];
    // W-summed IT, stride 24 words: st-group bases {0,16,0,16} mod 32 -> free 2-way
    __shared__ float  wB[RH][24];
    __shared__ float red[4];

    const int tid = threadIdx.x;
    const int bw = blockIdx.x;            // 0..9
    const int bh = blockIdx.y;            // 0..5
    const int bz = blockIdx.z;            // 0..17
    const int b  = bz / NCH;
    const int c  = bz - b * NCH;
    const int w0 = bw * TW;
    const int h0 = bh * TH;
    const int d0 = c * CH;
    const int dEnd = min(d0 + CH, DIM_D);

    const size_t plane = (size_t)DIM_H * DIM_W;
    const float* Ib = I + (size_t)b * DIM_D * plane;
    const float* Tb = T + (size_t)b * DIM_D * plane;

    // per-thread output coords: 2 stacked pixels at (hb, hb+1) x wo
    const int wo = tid & 15;
    const int hb = (tid >> 4) << 1;

    // region-load items: item0 = tid (all), item1 = tid+256 (tid<64 only)
    const int r0 = tid >> 3;
    const int c40 = (tid & 7) << 2;
    const int gh0 = h0 - 4 + r0;
    const int gw0 = w0 - 8 + c40;
    const bool inb0 = (gh0 >= 0 && gh0 < DIM_H && gw0 >= 0 && gw0 <= DIM_W - 4);
    const size_t off0 = inb0 ? ((size_t)gh0 * DIM_W + gw0) : 0;
    const int it1 = tid + 256;
    const int r1 = it1 >> 3;
    const int c41 = (it1 & 7) << 2;
    const int gh1 = h0 - 4 + r1;
    const int gw1 = w0 - 8 + c41;
    const bool inb1 = (tid < 64) && (gh1 >= 0 && gh1 < DIM_H && gw1 >= 0 && gw1 <= DIM_W - 4);
    const size_t off1 = inb1 ? ((size_t)gh1 * DIM_W + gw1) : 0;

    const float4 z4 = make_float4(0.f, 0.f, 0.f, 0.f);

    // 9-slot D-rings (slot index static via unroll-9) + running sums, 5 fields x 2 px
    float rgI[2][9], rgT[2][9], rgII[2][9], rgTT[2][9], rgIT[2][9];
    float rnI[2], rnT[2], rnII[2], rnTT[2], rnIT[2];
#pragma unroll
    for (int p = 0; p < 2; ++p) {
        rnI[p] = rnT[p] = rnII[p] = rnTT[p] = rnIT[p] = 0.0f;
#pragma unroll
        for (int j = 0; j < 9; ++j) {
            rgI[p][j] = rgT[p][j] = rgII[p][j] = rgTT[p][j] = rgIT[p][j] = 0.0f;
        }
    }
    float acc = 0.0f;

    const int sStart = d0 - 4;
    int cur = 0;

    // ---- prologue: preload slice sStart into buf 0 ----
    if (sStart >= 0) {
        const float* Is = Ib + (size_t)sStart * plane;
        const float* Ts = Tb + (size_t)sStart * plane;
        float4 li0 = inb0 ? *reinterpret_cast<const float4*>(Is + off0) : z4;
        float4 lt0 = inb0 ? *reinterpret_cast<const float4*>(Ts + off0) : z4;
        *reinterpret_cast<float4*>(&sR[0][0][r0][c40]) = li0;
        *reinterpret_cast<float4*>(&sR[0][1][r0][c40]) = lt0;
        if (tid < 64) {
            float4 li1 = inb1 ? *reinterpret_cast<const float4*>(Is + off1) : z4;
            float4 lt1 = inb1 ? *reinterpret_cast<const float4*>(Ts + off1) : z4;
            *reinterpret_cast<float4*>(&sR[0][0][r1][c41]) = li1;
            *reinterpret_cast<float4*>(&sR[0][1][r1][c41]) = lt1;
        }
    }
    __syncthreads();

    for (int t = 0; t < 3; ++t) {
#pragma unroll
        for (int j = 0; j < 9; ++j) {
            const int idx = t * 9 + j;               // 0..26
            const int s = sStart + idx;              // current slice
            const int sn = s + 1;                    // next slice
            const bool vs = (s >= 0) && (s < DIM_D);
            const bool vn = (idx < 26) && (sn >= 0) && (sn < DIM_D);

            // ---- 1. issue next-slice global loads into registers ----
            float4 li0 = z4, lt0 = z4, li1 = z4, lt1 = z4;
            if (vn) {
                const float* Is = Ib + (size_t)sn * plane;
                const float* Ts = Tb + (size_t)sn * plane;
                if (inb0) {
                    li0 = *reinterpret_cast<const float4*>(Is + off0);
                    lt0 = *reinterpret_cast<const float4*>(Ts + off0);
                }
                if (inb1) {
                    li1 = *reinterpret_cast<const float4*>(Is + off1);
                    lt1 = *reinterpret_cast<const float4*>(Ts + off1);
                }
            }

            // ---- 2. stage 1: 9-wide W sums (sliding, 4-output groups) ----
            if (vs && tid < 160) {
                const int r = tid >> 2;
                const int g = tid & 3;
                const float* rI_ = &sR[cur][0][r][0];
                const float* rT_ = &sR[cur][1][r][0];
                const float4 ia = *reinterpret_cast<const float4*>(rI_ + ((g + 1) << 2));
                const float4 ib = *reinterpret_cast<const float4*>(rI_ + ((g + 2) << 2));
                const float4 ic = *reinterpret_cast<const float4*>(rI_ + ((g + 3) << 2));
                const float4 ta = *reinterpret_cast<const float4*>(rT_ + ((g + 1) << 2));
                const float4 tb = *reinterpret_cast<const float4*>(rT_ + ((g + 2) << 2));
                const float4 tc = *reinterpret_cast<const float4*>(rT_ + ((g + 3) << 2));
                float iv[12] = {ia.x, ia.y, ia.z, ia.w, ib.x, ib.y, ib.z, ib.w, ic.x, ic.y, ic.z, ic.w};
                float tv[12] = {ta.x, ta.y, ta.z, ta.w, tb.x, tb.y, tb.z, tb.w, tc.x, tc.y, tc.z, tc.w};

                float aI = 0.f, aT = 0.f, aII = 0.f, aTT = 0.f, aIT = 0.f;
#pragma unroll
                for (int k = 0; k < 9; ++k) {
                    aI += iv[k];
                    aT += tv[k];
                    aII = fmaf(iv[k], iv[k], aII);
                    aTT = fmaf(tv[k], tv[k], aTT);
                    aIT = fmaf(iv[k], tv[k], aIT);
                }
                wA[r][(g << 2)] = make_float4(aI, aT, aII, aTT);
                wB[r][(g << 2)] = aIT;
#pragma unroll
                for (int q = 1; q < 4; ++q) {
                    const float ni = iv[8 + q], oi = iv[q - 1];
                    const float nt = tv[8 + q], ot = tv[q - 1];
                    aI += ni - oi;
                    aT += nt - ot;
                    aII = fmaf(ni, ni, fmaf(oi, -oi, aII));
                    aTT = fmaf(nt, nt, fmaf(ot, -ot, aTT));
                    aIT = fmaf(ni, nt, fmaf(oi, -ot, aIT));
                    wA[r][(g << 2) + q] = make_float4(aI, aT, aII, aTT);
                    wB[r][(g << 2) + q] = aIT;
                }
            }
            __syncthreads();

            // ---- 3. stage 2: 9-tall H sums, 2 stacked px via window overlap ----
            float s2I[2], s2T[2], s2II[2], s2TT[2], s2IT[2];
            s2I[0] = s2T[0] = s2II[0] = s2TT[0] = s2IT[0] = 0.f;
            s2I[1] = s2T[1] = s2II[1] = s2TT[1] = s2IT[1] = 0.f;
            if (vs) {
                const float4 A0 = wA[hb][wo];
                const float  b0 = wB[hb][wo];
                float4 S = A0;
                float  sb = b0;
#pragma unroll
                for (int k = 1; k < 9; ++k) {
                    const float4 A = wA[hb + k][wo];
                    S.x += A.x; S.y += A.y; S.z += A.z; S.w += A.w;
                    sb += wB[hb + k][wo];
                }
                const float4 A9 = wA[hb + 9][wo];
                const float  b9 = wB[hb + 9][wo];
                s2I[0] = S.x; s2T[0] = S.y; s2II[0] = S.z; s2TT[0] = S.w; s2IT[0] = sb;
                s2I[1]  = S.x - A0.x + A9.x;
                s2T[1]  = S.y - A0.y + A9.y;
                s2II[1] = S.z - A0.z + A9.z;
                s2TT[1] = S.w - A0.w + A9.w;
                s2IT[1] = sb  - b0   + b9;
            }

            // ---- 4. D-rings: static slot j (no shifting) ----
#pragma unroll
            for (int p = 0; p < 2; ++p) {
                rnI[p]  += s2I[p]  - rgI[p][j];   rgI[p][j]  = s2I[p];
                rnT[p]  += s2T[p]  - rgT[p][j];   rgT[p][j]  = s2T[p];
                rnII[p] += s2II[p] - rgII[p][j];  rgII[p][j] = s2II[p];
                rnTT[p] += s2TT[p] - rgTT[p][j];  rgTT[p][j] = s2TT[p];
                rnIT[p] += s2IT[p] - rgIT[p][j];  rgIT[p][j] = s2IT[p];
            }

            // ---- 5. emit for depth s-4 ----
            if (s >= d0 + 4 && (s - 4) < dEnd) {
#pragma unroll
                for (int p = 0; p < 2; ++p) {
                    const float cross = rnIT[p] - rnI[p] * rnT[p] * INV_K;
                    const float i_var = rnII[p] - rnI[p] * rnI[p] * INV_K;
                    const float t_var = rnTT[p] - rnT[p] * rnT[p] * INV_K;
                    acc += cross * cross / (t_var * i_var + 1e-5f);
                }
            }

            // ---- 6. commit next-slice registers into other buffer ----
            if (vn) {
                const int nb = cur ^ 1;
                *reinterpret_cast<float4*>(&sR[nb][0][r0][c40]) = li0;
                *reinterpret_cast<float4*>(&sR[nb][1][r0][c40]) = lt0;
                if (tid < 64) {
                    *reinterpret_cast<float4*>(&sR[nb][0][r1][c41]) = li1;
                    *reinterpret_cast<float4*>(&sR[nb][1][r1][c41]) = lt1;
                }
            }
            __syncthreads();
            cur ^= 1;
        }
    }

    // ---- block reduction ----
#pragma unroll
    for (int off = 32; off > 0; off >>= 1) acc += __shfl_down(acc, off, 64);
    if ((tid & 63) == 0) red[tid >> 6] = acc;
    __syncthreads();
    if (tid == 0) {
        const float bs = red[0] + red[1] + red[2] + red[3];
        atomicAdd(out, bs * (float)(-1.0 / NTOT));
    }
}

extern "C" void kernel_launch(void* const* d_in, const int* in_sizes, int n_in,
                              void* d_out, int out_size, void* d_ws, size_t ws_size,
                              hipStream_t stream) {
    const float* I = (const float*)d_in[0];
    const float* T = (const float*)d_in[1];
    float* out = (float*)d_out;

    zero_out_kernel<<<dim3(1), dim3(1), 0, stream>>>(out);

    dim3 grid(DIM_W / TW, DIM_H / TH, DIM_B * NCH); // 10 x 6 x 18 = 1080
    dim3 block(256);
    lncc3d_kernel<<<grid, block, 0, stream>>>(I, T, out);
}